// Round 1
// 691.630 us; speedup vs baseline: 1.0080x; 1.0080x over previous
//
#include <hip/hip_runtime.h>

using bf16x8 = __attribute__((ext_vector_type(8))) short;
using f32x4  = __attribute__((ext_vector_type(4))) float;

__device__ __forceinline__ ushort f2bf(float f) {
    union { float f; uint i; } v; v.f = f;
    uint r = v.i + 0x7fffu + ((v.i >> 16) & 1u);
    return (ushort)(r >> 16);
}
// tanh(x1) * sigmoid(x2) with 2 exp + 1 rcp
__device__ __forceinline__ float gate1(float x1, float x2) {
    float e1 = __expf(2.f * x1);
    float e2 = __expf(-x2);
    return (e1 - 1.f) * __builtin_amdgcn_rcpf((e1 + 1.f) * (1.f + e2));
}

// ---- fp32 [R,C] -> bf16 [C,R] 32x32 tile transpose+convert (device helper) ----
__device__ __forceinline__ void transpose_tile(const float* __restrict__ src,
                                               ushort* __restrict__ dst,
                                               int R, int C, int bx, int by,
                                               float (*t)[33]) {
    int c0 = bx << 5, r0 = by << 5;
    int x = threadIdx.x & 31, y = threadIdx.x >> 5;  // y in 0..7
#pragma unroll
    for (int j = 0; j < 4; j++)
        t[y + 8 * j][x] = src[(size_t)(r0 + y + 8 * j) * C + c0 + x];
    __syncthreads();
#pragma unroll
    for (int j = 0; j < 4; j++)
        dst[(size_t)(c0 + y + 8 * j) * R + r0 + x] = f2bf(t[x][y + 8 * j]);
}

// ---------------- fused prep: W_out^T (4096 blocks) | W_h2att^T (1024) | h cvt (256) ----
// One launch so the three independent jobs overlap instead of serializing on the stream.
__global__ __launch_bounds__(256) void k_prep(const float* __restrict__ h,
                                              ushort* __restrict__ hbf,
                                              const float* __restrict__ W1,
                                              ushort* __restrict__ WT1,
                                              const float* __restrict__ W2,
                                              ushort* __restrict__ WT2) {
    __shared__ float t[32][33];
    int bid = blockIdx.x;
    if (bid < 4096) {                       // W_out: 2048x2048, 64x64 tiles
        transpose_tile(W2, WT2, 2048, 2048, bid & 63, bid >> 6, t);
    } else if (bid < 4096 + 1024) {         // W_h2att: 1024x1024, 32x32 tiles
        int r = bid - 4096;
        transpose_tile(W1, WT1, 1024, 1024, r & 31, r >> 5, t);
    } else {                                // h -> bf16, 256 blocks x 1024 floats
        int r = bid - 5120;
        int i = (r * 256 + threadIdx.x) * 4;
        float4 v = *(const float4*)(h + i);
        uint2 o;
        o.x = (uint)f2bf(v.x) | ((uint)f2bf(v.y) << 16);
        o.y = (uint)f2bf(v.z) | ((uint)f2bf(v.w) << 16);
        *(uint2*)(hbf + i) = o;
    }
}

// ---------------- GEMM: Cpart[z] = A[M,K] @ BT[N,K]^T (split-K, fp32 partials) ----
// 64x64 tile, BK=32, 4 waves in 2x2, each wave 2x2 mfma_f32_16x16x32_bf16 frags.
__global__ __launch_bounds__(256) void k_gemm_bt(const ushort* __restrict__ A,
                                                 const ushort* __restrict__ BT,
                                                 float* __restrict__ Cp,
                                                 int M, int N, int K, int kchunk) {
    __shared__ ushort As[64 * 40];   // pad 32->40 elems: 80B row stride, 2-way bank (free)
    __shared__ ushort Bs[64 * 40];
    const int tid = threadIdx.x;
    const int n0 = blockIdx.x << 6, m0 = blockIdx.y << 6;
    const int k0 = blockIdx.z * kchunk;
    const int wave = tid >> 6, lane = tid & 63;
    const int wm = (wave >> 1) << 5, wn = (wave & 1) << 5;
    const int lr = lane & 15, lq = lane >> 4;
    const int srow = tid >> 2, scol = (tid & 3) << 3;

    f32x4 acc00 = {0.f, 0.f, 0.f, 0.f}, acc01 = acc00, acc10 = acc00, acc11 = acc00;
    const ushort* Ap = A + (size_t)(m0 + srow) * K + k0 + scol;
    const ushort* Bp = BT + (size_t)(n0 + srow) * K + k0 + scol;
    ushort* asd = &As[srow * 40 + scol];
    ushort* bsd = &Bs[srow * 40 + scol];

    for (int k = 0; k < kchunk; k += 32) {
        *(uint4*)asd = *(const uint4*)(Ap + k);
        *(uint4*)bsd = *(const uint4*)(Bp + k);
        __syncthreads();
        bf16x8 a0 = *(const bf16x8*)&As[(wm + lr) * 40 + (lq << 3)];
        bf16x8 a1 = *(const bf16x8*)&As[(wm + 16 + lr) * 40 + (lq << 3)];
        bf16x8 b0 = *(const bf16x8*)&Bs[(wn + lr) * 40 + (lq << 3)];
        bf16x8 b1 = *(const bf16x8*)&Bs[(wn + 16 + lr) * 40 + (lq << 3)];
        acc00 = __builtin_amdgcn_mfma_f32_16x16x32_bf16(a0, b0, acc00, 0, 0, 0);
        acc01 = __builtin_amdgcn_mfma_f32_16x16x32_bf16(a0, b1, acc01, 0, 0, 0);
        acc10 = __builtin_amdgcn_mfma_f32_16x16x32_bf16(a1, b0, acc10, 0, 0, 0);
        acc11 = __builtin_amdgcn_mfma_f32_16x16x32_bf16(a1, b1, acc11, 0, 0, 0);
        __syncthreads();
    }
    // C/D layout: col = lane&15, row = (lane>>4)*4 + reg  [m89/m91 verified]
    float* Cb = Cp + (size_t)blockIdx.z * M * N + (size_t)(m0 + wm + lq * 4) * N + n0 + wn + lr;
#pragma unroll
    for (int r = 0; r < 4; r++) {
        Cb[(size_t)r * N]             = acc00[r];
        Cb[(size_t)r * N + 16]        = acc01[r];
        Cb[(size_t)(r + 16) * N]      = acc10[r];
        Cb[(size_t)(r + 16) * N + 16] = acc11[r];
    }
}

// ---------------- reduce 4 split-K partials + bias(fp32) -> fp32 ----------------
__global__ __launch_bounds__(256) void k_reduce_bias(const float* __restrict__ part,
                                                     const float* __restrict__ bias,
                                                     float* __restrict__ outp,
                                                     int MN, int Nmask) {
    int idx = blockIdx.x * 256 + threadIdx.x;
    float s = bias[idx & Nmask];
#pragma unroll
    for (int ks = 0; ks < 4; ks++) s += part[ks * MN + idx];
    outp[idx] = s;
}

// ---------------- scores: one wave per (b,s), pure fp32 ----------------
__global__ __launch_bounds__(256) void k_scores(const float* __restrict__ p,
                                                const float* __restrict__ att_h,
                                                const float* __restrict__ w_alpha,
                                                const float* __restrict__ b_alpha,
                                                float* __restrict__ scores) {
    int wid = (blockIdx.x << 2) + (threadIdx.x >> 6);  // 0..50175 = b*196+s
    int lane = threadIdx.x & 63;
    int b = wid / 196;
    const float* pr = p + (size_t)wid * 1024 + lane * 8;
    float4 p1a = *(const float4*)pr;
    float4 p1b = *(const float4*)(pr + 4);
    float4 p2a = *(const float4*)(pr + 512);
    float4 p2b = *(const float4*)(pr + 516);
    const float* ah = att_h + ((size_t)b << 10) + lane * 8;
    float4 a1a = *(const float4*)ah;
    float4 a1b = *(const float4*)(ah + 4);
    float4 a2a = *(const float4*)(ah + 512);
    float4 a2b = *(const float4*)(ah + 516);
    const float* wa = w_alpha + lane * 8;
    float4 w0 = *(const float4*)wa;
    float4 w1 = *(const float4*)(wa + 4);
    float sum = gate1(p1a.x + a1a.x, p2a.x + a2a.x) * w0.x
              + gate1(p1a.y + a1a.y, p2a.y + a2a.y) * w0.y
              + gate1(p1a.z + a1a.z, p2a.z + a2a.z) * w0.z
              + gate1(p1a.w + a1a.w, p2a.w + a2a.w) * w0.w
              + gate1(p1b.x + a1b.x, p2b.x + a2b.x) * w1.x
              + gate1(p1b.y + a1b.y, p2b.y + a2b.y) * w1.y
              + gate1(p1b.z + a1b.z, p2b.z + a2b.z) * w1.z
              + gate1(p1b.w + a1b.w, p2b.w + a2b.w) * w1.w;
#pragma unroll
    for (int off = 32; off; off >>= 1) sum += __shfl_down(sum, off);
    if (lane == 0) scores[wid] = sum + b_alpha[0];
}

// ---- fused softmax + att_res[b,f] = sum_s w[b,s]*feats[b,s,f]; fp32 in, bf16 out ----
// Each (b, f-half) block recomputes the 196-wide softmax in LDS (duplicated 2x per b,
// ~free) -- removes the standalone softmax launch. Pool loop 14-deep (196 = 14*14).
__global__ __launch_bounds__(256) void k_attres_sm(const float* __restrict__ feats,
                                                   const float* __restrict__ scores,
                                                   ushort* __restrict__ att_res) {
    int b = blockIdx.x >> 1, fh = blockIdx.x & 1;
    __shared__ float wl[196];
    __shared__ float red[16];
    int t = threadIdx.x;
    // --- softmax over scores[b, 0:196] ---
    float v = (t < 196) ? scores[b * 196 + t] : -3.4e38f;
    float m = v;
#pragma unroll
    for (int off = 32; off; off >>= 1) m = fmaxf(m, __shfl_down(m, off));
    int wv = t >> 6, ln = t & 63;
    if (ln == 0) red[wv] = m;
    __syncthreads();
    if (t == 0) red[8] = fmaxf(fmaxf(red[0], red[1]), fmaxf(red[2], red[3]));
    __syncthreads();
    float M = red[8];
    float e = (t < 196) ? __expf(v - M) : 0.f;
    float s = e;
#pragma unroll
    for (int off = 32; off; off >>= 1) s += __shfl_down(s, off);
    if (ln == 0) red[wv + 4] = s;
    __syncthreads();
    if (t == 0) red[9] = 1.f / (red[4] + red[5] + red[6] + red[7]);
    __syncthreads();
    if (t < 196) wl[t] = e * red[9];
    __syncthreads();
    // --- weighted pooling, 14 x 16B loads in flight per lane ---
    int f = (fh << 10) + t * 4;
    const float* base = feats + (size_t)b * 196 * 2048 + f;
    float a0 = 0.f, a1 = 0.f, a2 = 0.f, a3 = 0.f;
    for (int s0 = 0; s0 < 196; s0 += 14) {
        float4 q[14];
        float w[14];
#pragma unroll
        for (int j = 0; j < 14; j++) q[j] = *(const float4*)(base + (size_t)(s0 + j) * 2048);
#pragma unroll
        for (int j = 0; j < 14; j++) w[j] = wl[s0 + j];
#pragma unroll
        for (int j = 0; j < 14; j++) {
            a0 += w[j] * q[j].x;
            a1 += w[j] * q[j].y;
            a2 += w[j] * q[j].z;
            a3 += w[j] * q[j].w;
        }
    }
    uint2 o;
    o.x = (uint)f2bf(a0) | ((uint)f2bf(a1) << 16);
    o.y = (uint)f2bf(a2) | ((uint)f2bf(a3) << 16);
    *(uint2*)(att_res + ((size_t)b << 11) + f) = o;
}

// ---- reduce 2 split-K partials + bias + tanh*sigmoid gate -> fp32 out ----
__global__ __launch_bounds__(256) void k_gate_out(const float* __restrict__ part,
                                                  const float* __restrict__ b_out,
                                                  float* __restrict__ outp) {
    int idx = blockIdx.x * 256 + threadIdx.x;  // 0..262143
    int b = idx >> 10, i = idx & 1023;
    int c1 = (b << 11) + i;
    const int MN = 256 * 2048;
    float o1 = b_out[i];
    float o2 = b_out[i + 1024];
#pragma unroll
    for (int ks = 0; ks < 2; ks++) {
        o1 += part[ks * MN + c1];
        o2 += part[ks * MN + c1 + 1024];
    }
    outp[idx] = gate1(o1, o2);
}

extern "C" void kernel_launch(void* const* d_in, const int* in_sizes, int n_in,
                              void* d_out, int out_size, void* d_ws, size_t ws_size,
                              hipStream_t stream) {
    const float* h         = (const float*)d_in[0];  // [256,1024] fp32
    const float* att_feats = (const float*)d_in[1];  // [256,196,2048]
    const float* p_att     = (const float*)d_in[2];  // [256,196,1024]
    const float* W_h2att   = (const float*)d_in[3];  // [1024,1024]
    const float* b_h2att   = (const float*)d_in[4];  // [1024]
    const float* w_alpha   = (const float*)d_in[5];  // [512]
    const float* b_alpha   = (const float*)d_in[6];  // [1]
    const float* W_out     = (const float*)d_in[7];  // [2048,2048]
    const float* b_out     = (const float*)d_in[8];  // [2048]
    float* outp = (float*)d_out;                     // [256,1024] fp32

    char* w = (char*)d_ws;
    const size_t KB = 1024;
    ushort* hbf     = (ushort*)w;                         // [0, 0.5MB)
    ushort* WT1     = (ushort*)(w + 512 * KB);            // [0.5, 2.5MB)
    ushort* WT2     = (ushort*)(w + 2560 * KB);           // [2.5, 10.5MB)
    float*  part1   = (float*)(w + 10752 * KB);           // [10.5, 14.5MB) gemm1 split4
    float*  part5   = (float*)(w + 10752 * KB);           // same region, gemm2 split2 (part1 dead)
    float*  att_h   = (float*)(w + 14848 * KB);           // [14.5, 15.5MB)
    float*  scores  = (float*)(w + 15872 * KB);           // [15.5, 15.75MB)
    ushort* att_res = (ushort*)(w + 16128 * KB);          // [15.75, 16.75MB)

    // fused prep: W_out^T || W_h2att^T || h->bf16 in ONE launch (independent jobs overlap)
    k_prep<<<5376, 256, 0, stream>>>(h, hbf, W_h2att, WT1, W_out, WT2);
    // att_h = h @ W_h2att (split-K=4, 256 blocks) ; + bias
    k_gemm_bt<<<dim3(16, 4, 4), 256, 0, stream>>>(hbf, WT1, part1, 256, 1024, 1024, 256);
    k_reduce_bias<<<1024, 256, 0, stream>>>(part1, b_h2att, att_h, 256 * 1024, 1023);
    // scores (fp32), then fused softmax+pooling (fp32 -> bf16)
    k_scores<<<12544, 256, 0, stream>>>(p_att, att_h, w_alpha, b_alpha, scores);
    k_attres_sm<<<512, 256, 0, stream>>>(att_feats, scores, att_res);
    // out = att_res @ W_out (split-K=2, 256 blocks) ; + bias + gate
    k_gemm_bt<<<dim3(32, 4, 2), 256, 0, stream>>>(att_res, WT2, part5, 256, 2048, 2048, 1024);
    k_gate_out<<<1024, 256, 0, stream>>>(part5, b_out, outp);
}

// Round 2
// 690.971 us; speedup vs baseline: 1.0089x; 1.0010x over previous
//
#include <hip/hip_runtime.h>

using bf16x8 = __attribute__((ext_vector_type(8))) short;
using f32x4  = __attribute__((ext_vector_type(4))) float;

__device__ __forceinline__ ushort f2bf(float f) {
    union { float f; uint i; } v; v.f = f;
    uint r = v.i + 0x7fffu + ((v.i >> 16) & 1u);
    return (ushort)(r >> 16);
}
// tanh(x1) * sigmoid(x2) with 2 exp + 1 rcp
__device__ __forceinline__ float gate1(float x1, float x2) {
    float e1 = __expf(2.f * x1);
    float e2 = __expf(-x2);
    return (e1 - 1.f) * __builtin_amdgcn_rcpf((e1 + 1.f) * (1.f + e2));
}

// ---- fp32 [R,C] -> bf16 [C,R] 32x32 tile transpose+convert (device helper) ----
__device__ __forceinline__ void transpose_tile(const float* __restrict__ src,
                                               ushort* __restrict__ dst,
                                               int R, int C, int bx, int by,
                                               float (*t)[33]) {
    int c0 = bx << 5, r0 = by << 5;
    int x = threadIdx.x & 31, y = threadIdx.x >> 5;  // y in 0..7
#pragma unroll
    for (int j = 0; j < 4; j++)
        t[y + 8 * j][x] = src[(size_t)(r0 + y + 8 * j) * C + c0 + x];
    __syncthreads();
#pragma unroll
    for (int j = 0; j < 4; j++)
        dst[(size_t)(c0 + y + 8 * j) * R + r0 + x] = f2bf(t[x][y + 8 * j]);
}

// ---------------- fused prep: W_out^T (4096 blocks) | W_h2att^T (1024) | h cvt (256) ----
__global__ __launch_bounds__(256) void k_prep(const float* __restrict__ h,
                                              ushort* __restrict__ hbf,
                                              const float* __restrict__ W1,
                                              ushort* __restrict__ WT1,
                                              const float* __restrict__ W2,
                                              ushort* __restrict__ WT2) {
    __shared__ float t[32][33];
    int bid = blockIdx.x;
    if (bid < 4096) {                       // W_out: 2048x2048, 64x64 tiles
        transpose_tile(W2, WT2, 2048, 2048, bid & 63, bid >> 6, t);
    } else if (bid < 4096 + 1024) {         // W_h2att: 1024x1024, 32x32 tiles
        int r = bid - 4096;
        transpose_tile(W1, WT1, 1024, 1024, r & 31, r >> 5, t);
    } else {                                // h -> bf16, 256 blocks x 1024 floats
        int r = bid - 5120;
        int i = (r * 256 + threadIdx.x) * 4;
        float4 v = *(const float4*)(h + i);
        uint2 o;
        o.x = (uint)f2bf(v.x) | ((uint)f2bf(v.y) << 16);
        o.y = (uint)f2bf(v.z) | ((uint)f2bf(v.w) << 16);
        *(uint2*)(hbf + i) = o;
    }
}

// ---------------- GEMM: Cpart[z] = A[M,K] @ BT[N,K]^T (split-K, fp32 partials) ----
// 64x64 tile, BK=32, 4 waves in 2x2, each wave 2x2 mfma_f32_16x16x32_bf16 frags.
__global__ __launch_bounds__(256) void k_gemm_bt(const ushort* __restrict__ A,
                                                 const ushort* __restrict__ BT,
                                                 float* __restrict__ Cp,
                                                 int M, int N, int K, int kchunk) {
    __shared__ ushort As[64 * 40];   // pad 32->40 elems: 80B row stride, 2-way bank (free)
    __shared__ ushort Bs[64 * 40];
    const int tid = threadIdx.x;
    const int n0 = blockIdx.x << 6, m0 = blockIdx.y << 6;
    const int k0 = blockIdx.z * kchunk;
    const int wave = tid >> 6, lane = tid & 63;
    const int wm = (wave >> 1) << 5, wn = (wave & 1) << 5;
    const int lr = lane & 15, lq = lane >> 4;
    const int srow = tid >> 2, scol = (tid & 3) << 3;

    f32x4 acc00 = {0.f, 0.f, 0.f, 0.f}, acc01 = acc00, acc10 = acc00, acc11 = acc00;
    const ushort* Ap = A + (size_t)(m0 + srow) * K + k0 + scol;
    const ushort* Bp = BT + (size_t)(n0 + srow) * K + k0 + scol;
    ushort* asd = &As[srow * 40 + scol];
    ushort* bsd = &Bs[srow * 40 + scol];

    for (int k = 0; k < kchunk; k += 32) {
        *(uint4*)asd = *(const uint4*)(Ap + k);
        *(uint4*)bsd = *(const uint4*)(Bp + k);
        __syncthreads();
        bf16x8 a0 = *(const bf16x8*)&As[(wm + lr) * 40 + (lq << 3)];
        bf16x8 a1 = *(const bf16x8*)&As[(wm + 16 + lr) * 40 + (lq << 3)];
        bf16x8 b0 = *(const bf16x8*)&Bs[(wn + lr) * 40 + (lq << 3)];
        bf16x8 b1 = *(const bf16x8*)&Bs[(wn + 16 + lr) * 40 + (lq << 3)];
        acc00 = __builtin_amdgcn_mfma_f32_16x16x32_bf16(a0, b0, acc00, 0, 0, 0);
        acc01 = __builtin_amdgcn_mfma_f32_16x16x32_bf16(a0, b1, acc01, 0, 0, 0);
        acc10 = __builtin_amdgcn_mfma_f32_16x16x32_bf16(a1, b0, acc10, 0, 0, 0);
        acc11 = __builtin_amdgcn_mfma_f32_16x16x32_bf16(a1, b1, acc11, 0, 0, 0);
        __syncthreads();
    }
    // C/D layout: col = lane&15, row = (lane>>4)*4 + reg  [m89/m91 verified]
    float* Cb = Cp + (size_t)blockIdx.z * M * N + (size_t)(m0 + wm + lq * 4) * N + n0 + wn + lr;
#pragma unroll
    for (int r = 0; r < 4; r++) {
        Cb[(size_t)r * N]             = acc00[r];
        Cb[(size_t)r * N + 16]        = acc01[r];
        Cb[(size_t)(r + 16) * N]      = acc10[r];
        Cb[(size_t)(r + 16) * N + 16] = acc11[r];
    }
}

// ---------------- reduce 4 split-K partials + bias(fp32) -> fp32 ----------------
__global__ __launch_bounds__(256) void k_reduce_bias(const float* __restrict__ part,
                                                     const float* __restrict__ bias,
                                                     float* __restrict__ outp,
                                                     int MN, int Nmask) {
    int idx = blockIdx.x * 256 + threadIdx.x;
    float s = bias[idx & Nmask];
#pragma unroll
    for (int ks = 0; ks < 4; ks++) s += part[ks * MN + idx];
    outp[idx] = s;
}

// ---- fused scores + softmax + pooling, one block per batch row ----
// Phase 1: 8 waves compute the 196 scores (wave w does s = w, w+8, ...).
// Phase 2: wave 0 does the softmax over 196 scores (lane j owns up to 4).
// Phase 3: 512 threads stream att_feats[b] (thread t owns f = 4t..4t+3), unroll 14.
__global__ __launch_bounds__(512) void k_att_fused(const float* __restrict__ p,
                                                   const float* __restrict__ att_h,
                                                   const float* __restrict__ w_alpha,
                                                   const float* __restrict__ b_alpha,
                                                   const float* __restrict__ feats,
                                                   ushort* __restrict__ att_res) {
    __shared__ float sc[196];
    __shared__ float wl[196];
    const int b = blockIdx.x;
    const int t = threadIdx.x, wave = t >> 6, lane = t & 63;

    // --- phase 1: scores ---
    const float* ah = att_h + ((size_t)b << 10) + lane * 8;
    float4 a1a = *(const float4*)ah;
    float4 a1b = *(const float4*)(ah + 4);
    float4 a2a = *(const float4*)(ah + 512);
    float4 a2b = *(const float4*)(ah + 516);
    const float* wa = w_alpha + lane * 8;
    float4 w0 = *(const float4*)wa;
    float4 w1 = *(const float4*)(wa + 4);
    float balpha = b_alpha[0];
    for (int s = wave; s < 196; s += 8) {
        const float* pr = p + (((size_t)(b * 196 + s)) << 10) + lane * 8;
        float4 p1a = *(const float4*)pr;
        float4 p1b = *(const float4*)(pr + 4);
        float4 p2a = *(const float4*)(pr + 512);
        float4 p2b = *(const float4*)(pr + 516);
        float sum = gate1(p1a.x + a1a.x, p2a.x + a2a.x) * w0.x
                  + gate1(p1a.y + a1a.y, p2a.y + a2a.y) * w0.y
                  + gate1(p1a.z + a1a.z, p2a.z + a2a.z) * w0.z
                  + gate1(p1a.w + a1a.w, p2a.w + a2a.w) * w0.w
                  + gate1(p1b.x + a1b.x, p2b.x + a2b.x) * w1.x
                  + gate1(p1b.y + a1b.y, p2b.y + a2b.y) * w1.y
                  + gate1(p1b.z + a1b.z, p2b.z + a2b.z) * w1.z
                  + gate1(p1b.w + a1b.w, p2b.w + a2b.w) * w1.w;
#pragma unroll
        for (int off = 32; off; off >>= 1) sum += __shfl_down(sum, off);
        if (lane == 0) sc[s] = sum + balpha;
    }
    __syncthreads();

    // --- phase 2: softmax by wave 0 (exp of -3.4e38 underflows to 0, masks only on writes) ---
    if (wave == 0) {
        float v0 = (lane < 196) ? sc[lane] : -3.4e38f;
        float v1 = (lane + 64 < 196) ? sc[lane + 64] : -3.4e38f;
        float v2 = (lane + 128 < 196) ? sc[lane + 128] : -3.4e38f;
        float v3 = (lane + 192 < 196) ? sc[lane + 192] : -3.4e38f;
        float m = fmaxf(fmaxf(v0, v1), fmaxf(v2, v3));
#pragma unroll
        for (int off = 32; off; off >>= 1) m = fmaxf(m, __shfl_xor(m, off));
        float e0 = __expf(v0 - m), e1 = __expf(v1 - m);
        float e2 = __expf(v2 - m), e3 = __expf(v3 - m);
        float ssum = e0 + e1 + e2 + e3;
#pragma unroll
        for (int off = 32; off; off >>= 1) ssum += __shfl_xor(ssum, off);
        float inv = 1.f / ssum;
        if (lane < 196)       wl[lane]       = e0 * inv;
        if (lane + 64 < 196)  wl[lane + 64]  = e1 * inv;
        if (lane + 128 < 196) wl[lane + 128] = e2 * inv;
        if (lane + 192 < 196) wl[lane + 192] = e3 * inv;
    }
    __syncthreads();

    // --- phase 3: weighted pooling, 14 x 16B loads in flight per lane ---
    const int f = t << 2;
    const float* base = feats + (size_t)b * 196 * 2048 + f;
    float a0 = 0.f, a1 = 0.f, a2 = 0.f, a3 = 0.f;
    for (int s0 = 0; s0 < 196; s0 += 14) {
        float4 q[14];
        float w[14];
#pragma unroll
        for (int j = 0; j < 14; j++) q[j] = *(const float4*)(base + (size_t)(s0 + j) * 2048);
#pragma unroll
        for (int j = 0; j < 14; j++) w[j] = wl[s0 + j];
#pragma unroll
        for (int j = 0; j < 14; j++) {
            a0 += w[j] * q[j].x;
            a1 += w[j] * q[j].y;
            a2 += w[j] * q[j].z;
            a3 += w[j] * q[j].w;
        }
    }
    uint2 o;
    o.x = (uint)f2bf(a0) | ((uint)f2bf(a1) << 16);
    o.y = (uint)f2bf(a2) | ((uint)f2bf(a3) << 16);
    *(uint2*)(att_res + ((size_t)b << 11) + f) = o;
}

// ---- reduce 4 split-K partials + bias + tanh*sigmoid gate -> fp32 out ----
__global__ __launch_bounds__(256) void k_gate_out(const float* __restrict__ part,
                                                  const float* __restrict__ b_out,
                                                  float* __restrict__ outp) {
    int idx = blockIdx.x * 256 + threadIdx.x;  // 0..262143
    int b = idx >> 10, i = idx & 1023;
    int c1 = (b << 11) + i;
    const int MN = 256 * 2048;
    float o1 = b_out[i];
    float o2 = b_out[i + 1024];
#pragma unroll
    for (int ks = 0; ks < 4; ks++) {
        o1 += part[ks * MN + c1];
        o2 += part[ks * MN + c1 + 1024];
    }
    outp[idx] = gate1(o1, o2);
}

extern "C" void kernel_launch(void* const* d_in, const int* in_sizes, int n_in,
                              void* d_out, int out_size, void* d_ws, size_t ws_size,
                              hipStream_t stream) {
    const float* h         = (const float*)d_in[0];  // [256,1024] fp32
    const float* att_feats = (const float*)d_in[1];  // [256,196,2048]
    const float* p_att     = (const float*)d_in[2];  // [256,196,1024]
    const float* W_h2att   = (const float*)d_in[3];  // [1024,1024]
    const float* b_h2att   = (const float*)d_in[4];  // [1024]
    const float* w_alpha   = (const float*)d_in[5];  // [512]
    const float* b_alpha   = (const float*)d_in[6];  // [1]
    const float* W_out     = (const float*)d_in[7];  // [2048,2048]
    const float* b_out     = (const float*)d_in[8];  // [2048]
    float* outp = (float*)d_out;                     // [256,1024] fp32

    char* w = (char*)d_ws;
    const size_t KB = 1024;
    ushort* hbf     = (ushort*)w;                         // [0, 0.5MB)
    ushort* WT1     = (ushort*)(w + 512 * KB);            // [0.5, 2.5MB)
    ushort* WT2     = (ushort*)(w + 2560 * KB);           // [2.5, 10.5MB)
    float*  part1   = (float*)(w + 10752 * KB);           // [10.5, 14.5MB) gemm1 split4
    float*  part5   = (float*)(w + 10752 * KB);           // [10.5, 18.5MB) gemm2 split4 (part1 dead)
    float*  att_h   = (float*)(w + 18944 * KB);           // [18.5, 19.5MB)
    ushort* att_res = (ushort*)(w + 19968 * KB);          // [19.5, 20.5MB)

    // fused prep: W_out^T || W_h2att^T || h->bf16 in ONE launch
    k_prep<<<5376, 256, 0, stream>>>(h, hbf, W_h2att, WT1, W_out, WT2);
    // att_h = h @ W_h2att (split-K=4, 256 blocks) ; + bias
    k_gemm_bt<<<dim3(16, 4, 4), 256, 0, stream>>>(hbf, WT1, part1, 256, 1024, 1024, 256);
    k_reduce_bias<<<1024, 256, 0, stream>>>(part1, b_h2att, att_h, 256 * 1024, 1023);
    // fused scores + softmax + pooling, one block per batch row
    k_att_fused<<<256, 512, 0, stream>>>(p_att, att_h, w_alpha, b_alpha, att_feats, att_res);
    // out = att_res @ W_out (split-K=4, 512 blocks -> 2 blocks/CU) ; + bias + gate
    k_gemm_bt<<<dim3(32, 4, 4), 256, 0, stream>>>(att_res, WT2, part5, 256, 2048, 2048, 512);
    k_gate_out<<<1024, 256, 0, stream>>>(part5, b_out, outp);
}